// Round 2
// baseline (211.349 us; speedup 1.0000x reference)
//
#include <hip/hip_runtime.h>
#include <stdint.h>

#define D_EMB 128
#define HIDDEN 64
#define PACK_SCALE 1024.0f
#define INV_PACK (1.0f/1024.0f)

__device__ __forceinline__ uint32_t rotl32(uint32_t x, int r) {
    return (x << r) | (x >> (32 - r));
}

// Bit-exact JAX threefry2x32, PARTITIONABLE path (default since jax 0.4.36).
// key = jax.random.key(42) -> (k1,k2) = (0,42).
// Per element e: counts64 = e; x0 = hi32 = 0, x1 = lo32 = e;
// 32-bit draw = final_x0 ^ final_x1.
__device__ __forceinline__ uint32_t jax_threefry_bits_part(uint32_t e) {
    const uint32_t ks0 = 0u;
    const uint32_t ks1 = 42u;
    const uint32_t ks2 = 0x1BD11BDAu ^ 0u ^ 42u;
    uint32_t x0 = 0u + ks0;
    uint32_t x1 = e + ks1;
#define TF_R(r) { x0 += x1; x1 = rotl32(x1, (r)); x1 ^= x0; }
    TF_R(13) TF_R(15) TF_R(26) TF_R(6)
    x0 += ks1; x1 += ks2 + 1u;
    TF_R(17) TF_R(29) TF_R(16) TF_R(24)
    x0 += ks2; x1 += ks0 + 2u;
    TF_R(13) TF_R(15) TF_R(26) TF_R(6)
    x0 += ks0; x1 += ks1 + 3u;
    TF_R(17) TF_R(29) TF_R(16) TF_R(24)
    x0 += ks1; x1 += ks2 + 4u;
    TF_R(13) TF_R(15) TF_R(26) TF_R(6)
    x0 += ks2; x1 += ks0 + 5u;
#undef TF_R
    return x0 ^ x1;
}

// Kernel 1: per-node projections. Pcat[n][0:64] = embed[n] @ W1[0:128] + b1
//           Pcat[n][64:128] = embed[n] @ W1[128:256]
__global__ __launch_bounds__(128) void node_proj_kernel(
    const float* __restrict__ embed, const float* __restrict__ W1,
    const float* __restrict__ b1, float* __restrict__ Pcat) {
    __shared__ float e_lds[D_EMB];
    int n = blockIdx.x;
    int t = threadIdx.x;             // 0..127
    e_lds[t] = embed[(size_t)n * D_EMB + t];
    __syncthreads();
    int half = t >> 6;               // 0 -> P1 (col side), 1 -> P2 (row side)
    int k = t & 63;
    const float* w = W1 + (size_t)half * D_EMB * HIDDEN + k;
    float acc = (half == 0) ? b1[k] : 0.0f;
#pragma unroll 16
    for (int d = 0; d < D_EMB; d++) {
        acc += e_lds[d] * w[(size_t)d * HIDDEN];
    }
    Pcat[(size_t)n * (2 * HIDDEN) + t] = acc;
}

// Kernel 2: per-edge gate value, packed atomic accumulate into out[c*N+r].
__global__ __launch_bounds__(256) void edge_scatter_kernel(
    const int* __restrict__ ei, const float* __restrict__ Pcat,
    const float* __restrict__ W2, const float* __restrict__ b2,
    float* __restrict__ out, int E, int N) {
    __shared__ float w2s[HIDDEN];
    if (threadIdx.x < HIDDEN) w2s[threadIdx.x] = W2[threadIdx.x];
    __syncthreads();
    int e = blockIdx.x * blockDim.x + threadIdx.x;
    if (e >= E) return;
    int c = ei[e];
    int r = ei[E + e];
    if ((unsigned)c >= (unsigned)N || (unsigned)r >= (unsigned)N) return;

    const float4* p1 = (const float4*)(Pcat + (size_t)c * (2 * HIDDEN));
    const float4* p2 = (const float4*)(Pcat + (size_t)r * (2 * HIDDEN) + HIDDEN);
    const float4* w4 = (const float4*)w2s;
    float la = b2[0];
#pragma unroll
    for (int k = 0; k < HIDDEN / 4; k++) {
        float4 a = p1[k];
        float4 b = p2[k];
        float4 w = w4[k];
        la += fmaxf(a.x + b.x, 0.0f) * w.x + fmaxf(a.y + b.y, 0.0f) * w.y +
              fmaxf(a.z + b.z, 0.0f) * w.z + fmaxf(a.w + b.w, 0.0f) * w.w;
    }

    uint32_t bits = jax_threefry_bits_part((uint32_t)e);
    float u = __uint_as_float((bits >> 9) | 0x3f800000u) - 1.0f;
    // sigmoid(log(u) - log1p(-u) + la) == u / (u + (1-u)*exp(-la))
    float v = u / (u + (1.0f - u) * __expf(-la));

    atomicAdd(out + (size_t)c * N + r, PACK_SCALE + v);
}

// Kernel 3a: per-edge read both packed cells, compute final value.
__global__ __launch_bounds__(256) void edge_read_kernel(
    const int* __restrict__ ei, const float* __restrict__ out,
    float* __restrict__ vals, int E, int N) {
    int e = blockIdx.x * blockDim.x + threadIdx.x;
    if (e >= E) return;
    int c = ei[e];
    int r = ei[E + e];
    if ((unsigned)c >= (unsigned)N || (unsigned)r >= (unsigned)N) { return; }
    float a = out[(size_t)c * N + r];
    float b = out[(size_t)r * N + c];
    float cnt_a = truncf(a * INV_PACK);
    float s_a = a - PACK_SCALE * cnt_a;
    float cnt_b = truncf(b * INV_PACK);
    float s_b = b - PACK_SCALE * cnt_b;
    vals[e] = cnt_a * 0.5f * (s_a + s_b);
}

// Kernel 3b: per-edge write final value (idempotent across duplicates).
__global__ __launch_bounds__(256) void edge_write_kernel(
    const int* __restrict__ ei, const float* __restrict__ vals,
    float* __restrict__ out, int E, int N) {
    int e = blockIdx.x * blockDim.x + threadIdx.x;
    if (e >= E) return;
    int c = ei[e];
    int r = ei[E + e];
    if ((unsigned)c >= (unsigned)N || (unsigned)r >= (unsigned)N) return;
    out[(size_t)c * N + r] = vals[e];
}

extern "C" void kernel_launch(void* const* d_in, const int* in_sizes, int n_in,
                              void* d_out, int out_size, void* d_ws, size_t ws_size,
                              hipStream_t stream) {
    const float* embed = (const float*)d_in[0];
    const int*   ei    = (const int*)d_in[1];
    const float* W1    = (const float*)d_in[2];
    const float* b1    = (const float*)d_in[3];
    const float* W2    = (const float*)d_in[4];
    const float* b2    = (const float*)d_in[5];
    float* out = (float*)d_out;

    const int N = in_sizes[0] / D_EMB;      // 10000
    const int E = in_sizes[1] / 2;          // 640000

    float* Pcat = (float*)d_ws;                                   // N*128 floats
    float* vals = (float*)((char*)d_ws + (size_t)N * 2 * HIDDEN * sizeof(float)); // E floats

    // Zero the dense output (only nonzeros get rewritten later).
    hipMemsetAsync(d_out, 0, (size_t)out_size * sizeof(float), stream);

    node_proj_kernel<<<N, 128, 0, stream>>>(embed, W1, b1, Pcat);

    const int eb = 256;
    const int eg = (E + eb - 1) / eb;
    edge_scatter_kernel<<<eg, eb, 0, stream>>>(ei, Pcat, W2, b2, out, E, N);
    edge_read_kernel<<<eg, eb, 0, stream>>>(ei, out, vals, E, N);
    edge_write_kernel<<<eg, eb, 0, stream>>>(ei, vals, out, E, N);
}